// Round 8
// baseline (397.268 us; speedup 1.0000x reference)
//
#include <hip/hip_runtime.h>
#include <stdint.h>

// ---------------------------------------------------------------------------
// EmbraceNet fused: out[b,e] = relu(x_f @ W_f + b_f)[b,e],  f = idx[b,e]
// idx = categorical(key=42): partitionable threefry, bits = y0^y1 of
// threefry2x32((0,42), (0, (e*4096+b)*4+f)); argmax over bits>>9, strict >.
// PASS since R4 (absmax 0.031).
//
// R18: occupancy lever on the winning structure. R17 (92.5->86.5 us via
// XCD swizzle, FETCH 140->83 MB) runs 2 blocks/CU; every regression this
// session correlated with losing cross-block overlap (m114). This round:
// BK=32 double-buffer -> 32 KiB LDS -> 4 blocks/CU (__launch_bounds__
// (256,4); VGPR 124x4=496<=512). Skeleton unchanged from R10/R17: plain
// __syncthreads double-buffer, stage-next-then-compute, register
// selection-fold, dense epilogue, XCD swizzle. BK=32 staging/read
// addressing lifted verbatim from R13 (passed, 0 bank conflicts):
// LDS[row][slot] holds global k-chunk slot^((row>>1)&3); pre-swizzled
// global source, linear LDS dst. Flat 128-step loop (f = j>>5), fold at
// plane boundaries. Single variable vs R17: occupancy (129 barriers vs
// 68, but 4-way block overlap to hide them).
// ---------------------------------------------------------------------------

typedef short short8 __attribute__((ext_vector_type(8)));
typedef float floatx4 __attribute__((ext_vector_type(4)));

#define B_DIM 4096
#define K_DIM 1024
#define E_DIM 2048

__device__ __forceinline__ uint32_t rotl32(uint32_t x, uint32_t r) {
  return __builtin_amdgcn_alignbit(x, x, 32u - r);
}

__device__ __forceinline__ uint16_t f2bf(float x) {
  uint32_t u = __float_as_uint(x);
  u += 0x7FFFu + ((u >> 16) & 1u);
  return (uint16_t)(u >> 16);
}

// JAX threefry2x32, key = (0, 42)
__device__ __forceinline__ void threefry(uint32_t x0, uint32_t x1,
                                         uint32_t& o0, uint32_t& o1) {
  const uint32_t ks0 = 0u;
  const uint32_t ks1 = 42u;
  const uint32_t ks2 = 0x1BD11BDAu ^ 42u;
  x0 += ks0; x1 += ks1;
#define TF_R(r) { x0 += x1; x1 = rotl32(x1, r); x1 ^= x0; }
  TF_R(13) TF_R(15) TF_R(26) TF_R(6)
  x0 += ks1; x1 += ks2 + 1u;
  TF_R(17) TF_R(29) TF_R(16) TF_R(24)
  x0 += ks2; x1 += ks0 + 2u;
  TF_R(13) TF_R(15) TF_R(26) TF_R(6)
  x0 += ks0; x1 += ks1 + 3u;
  TF_R(17) TF_R(29) TF_R(16) TF_R(24)
  x0 += ks1; x1 += ks2 + 4u;
  TF_R(13) TF_R(15) TF_R(26) TF_R(6)
  x0 += ks2; x1 += ks0 + 5u;
#undef TF_R
  o0 = x0; o1 = x1;
}

// 8192 blocks x 256 threads. Every thread: issue x loads (8 floats) + W
// loads (4 floats), crunch 4 idx outputs (16 threefry) while loads fly,
// then store x bf16 (16B), idx byte, and W transposed tile via LDS.
__global__ __launch_bounds__(256) void prep_kernel(
    const float* __restrict__ x0, const float* __restrict__ x1,
    const float* __restrict__ x2, const float* __restrict__ x3,
    const float* __restrict__ W0, const float* __restrict__ W1,
    const float* __restrict__ W2, const float* __restrict__ W3,
    uint16_t* __restrict__ xb, uint16_t* __restrict__ Wt,
    uint8_t* __restrict__ idx1) {
  __shared__ float tile[32][33];
  const uint32_t g = blockIdx.x;       // 0..8191
  const int t = threadIdx.x;
  const int f = g >> 11;               // plane 0..3
  const uint32_t ip = g & 2047u;       // tile/chunk within plane

  // ---- issue x loads: plane f, 8 consecutive floats per thread ----
  const float* x = (f == 0) ? x0 : (f == 1) ? x1 : (f == 2) ? x2 : x3;
  const size_t xoff = ((size_t)ip * 256 + t) * 8;
  float4 v0 = *(const float4*)(x + xoff);
  float4 v1 = *(const float4*)(x + xoff + 4);

  // ---- issue W loads: 32x32 tile ip of plane f ----
  const float* W = (f == 0) ? W0 : (f == 1) ? W1 : (f == 2) ? W2 : W3;
  const int e0 = (int)(ip & 63) * 32, k0 = (int)(ip >> 6) * 32;
  const int tx = t & 31, ty = t >> 5;
  float wv[4];
#pragma unroll
  for (int i = 0; i < 4; ++i)
    wv[i] = W[(size_t)(k0 + ty + i * 8) * E_DIM + e0 + tx];

  // ---- threefry crunch: outputs o0..o0+3, pack 2 bits each ----
  const uint32_t o0i = (g * 256u + t) * 4u;
  uint32_t byte = 0;
#pragma unroll
  for (uint32_t q = 0; q < 4; ++q) {
    uint32_t c = (o0i + q) << 2;
    uint32_t best = 0, bi = 0;
#pragma unroll
    for (uint32_t ff = 0; ff < 4; ++ff) {
      uint32_t y0, y1;
      threefry(0u, c + ff, y0, y1);
      uint32_t m = (y0 ^ y1) >> 9;
      if (ff == 0) best = m;
      else if (m > best) { best = m; bi = ff; }
    }
    byte |= bi << (2 * q);
  }
  idx1[g * 256u + t] = (uint8_t)byte;

  // ---- x store: 8 bf16 = 16B ----
  {
    union { uint16_t h[8]; uint64_t q[2]; } p;
    p.h[0] = f2bf(v0.x); p.h[1] = f2bf(v0.y);
    p.h[2] = f2bf(v0.z); p.h[3] = f2bf(v0.w);
    p.h[4] = f2bf(v1.x); p.h[5] = f2bf(v1.y);
    p.h[6] = f2bf(v1.z); p.h[7] = f2bf(v1.w);
    uint64_t* dst = (uint64_t*)(xb + (size_t)f * B_DIM * K_DIM + xoff);
    dst[0] = p.q[0]; dst[1] = p.q[1];
  }

  // ---- W transpose via LDS ----
#pragma unroll
  for (int i = 0; i < 4; ++i) tile[ty + i * 8][tx] = wv[i];
  __syncthreads();
  {
    const int el = t >> 3, kc = (t & 7) * 4;
    union { uint16_t h[4]; uint64_t q; } p;
#pragma unroll
    for (int i = 0; i < 4; ++i) p.h[i] = f2bf(tile[kc + i][el]);
    uint16_t* dst = Wt + (size_t)f * E_DIM * K_DIM;
    *(uint64_t*)(dst + (size_t)(e0 + el) * K_DIM + k0 + kc) = p.q;
  }
}

__device__ __forceinline__ void async16(const uint16_t* g, uint16_t* lds) {
  __builtin_amdgcn_global_load_lds(
      (const __attribute__((address_space(1))) void*)g,
      (__attribute__((address_space(3))) void*)lds, 16, 0, 0);
}

#define PLANE_A ((size_t)B_DIM * K_DIM)
#define PLANE_B ((size_t)E_DIM * K_DIM)
#define BK 32

// 256 threads (4 waves, 2x2 of 64x64), 128x128 tile, BK=32 double-buffered
// LDS (32 KiB -> 4 blocks/CU), flat 128-step loop (f = j>>5), one
// __syncthreads per step. LDS row = 32 bf16 (64 B) = 4 slots x 16B; slot
// holds global k-chunk slot^((row>>1)&3) (R13-verified, 0 conflicts).
__global__ __launch_bounds__(256, 4) void gemm_fused(
    const uint16_t* __restrict__ Ab, const uint16_t* __restrict__ Bbt,
    const uint32_t* __restrict__ idx2,
    const float* __restrict__ bias0, const float* __restrict__ bias1,
    const float* __restrict__ bias2, const float* __restrict__ bias3,
    float* __restrict__ out) {
  __shared__ uint16_t As[2][128 * BK];   // 2 x 8 KiB
  __shared__ uint16_t Bs[2][128 * BK];   // 2 x 8 KiB

  const int tid = threadIdx.x;
  const int w = tid >> 6;        // 0..3
  const int l = tid & 63;

  // bijective XCD-chunked swizzle: 512 blocks = 8 XCDs x 64 contiguous
  const int flat = (int)(blockIdx.y * gridDim.x + blockIdx.x);
  const int swz = (flat & 7) * 64 + (flat >> 3);
  const int mBase = (swz >> 4) * 128;   // 32 m-tiles
  const int nBase = (swz & 15) * 128;   // 16 n-tiles

  const int wm = (w >> 1) * 64, wn = (w & 1) * 64;
  const int fr = l & 15, fq = l >> 4;

  // staging (R13-verified): lane l -> row sRow = l>>2 (of 16-row group),
  // slot = l&3; global k-chunk = slot ^ ((sRow>>1)&3).
  const int sRow = l >> 2;
  const int gck = ((l & 3) ^ ((sRow >> 1) & 3)) * 8;
  const uint16_t* aBase = Ab + (size_t)(mBase + 32 * w + sRow) * K_DIM + gck;
  const uint16_t* bBase = Bbt + (size_t)(nBase + 32 * w + sRow) * K_DIM + gck;

  // read-side: slot for global chunk fq of row (row bits 2:1 == fr bits)
  const int kread = (fq ^ ((fr >> 1) & 3)) * 8;

  // stage 32-K step t into buffer bf: 2 A-instrs + 2 B-instrs per wave
  auto stage = [&](int t, int bf) {
    const int f = t >> 5, ko = (t & 31) * BK;
    const uint16_t* pA = aBase + (size_t)f * PLANE_A + ko;
    const uint16_t* pB = bBase + (size_t)f * PLANE_B + ko;
    async16(pA, &As[bf][(2 * w + 0) * 512]);
    async16(pA + (size_t)16 * K_DIM, &As[bf][(2 * w + 1) * 512]);
    async16(pB, &Bs[bf][(2 * w + 0) * 512]);
    async16(pB + (size_t)16 * K_DIM, &Bs[bf][(2 * w + 1) * 512]);
  };

  // selection words in regs
  const int b_hi0 = (mBase + wm) >> 4;
  uint32_t iw[4][4];
#pragma unroll
  for (int ni = 0; ni < 4; ++ni) {
    int col = nBase + wn + ni * 16 + fr;
#pragma unroll
    for (int mi = 0; mi < 4; ++mi)
      iw[ni][mi] = idx2[(size_t)col * (B_DIM / 16) + b_hi0 + mi];
  }

  floatx4 acc[4][4] = {};
  floatx4 res[4][4] = {};

  stage(0, 0);
  __syncthreads();

  int buf = 0;
#pragma unroll 1
  for (int j = 0; j < 128; ++j) {
    if (j + 1 < 128) stage(j + 1, buf ^ 1);

    short8 a[4], b[4];
#pragma unroll
    for (int mi = 0; mi < 4; ++mi)
      a[mi] = *(const short8*)&As[buf][(wm + mi * 16 + fr) * BK + kread];
#pragma unroll
    for (int ni = 0; ni < 4; ++ni)
      b[ni] = *(const short8*)&Bs[buf][(wn + ni * 16 + fr) * BK + kread];
#pragma unroll
    for (int mi = 0; mi < 4; ++mi)
#pragma unroll
      for (int ni = 0; ni < 4; ++ni)
        acc[mi][ni] = __builtin_amdgcn_mfma_f32_16x16x32_bf16(
            a[mi], b[ni], acc[mi][ni], 0, 0, 0);

    // plane boundary: register-only selection fold, reset acc
    if ((j & 31) == 31) {
      const int f = j >> 5;
      const float* bias = (f == 0) ? bias0 : (f == 1) ? bias1
                        : (f == 2) ? bias2 : bias3;
#pragma unroll
      for (int ni = 0; ni < 4; ++ni) {
        float bvf = bias[nBase + wn + ni * 16 + fr];
#pragma unroll
        for (int mi = 0; mi < 4; ++mi) {
          uint32_t wd = iw[ni][mi];
#pragma unroll
          for (int r = 0; r < 4; ++r) {
            uint32_t sel = (wd >> (2 * (fq * 4 + r))) & 3u;
            if (sel == (uint32_t)f) res[mi][ni][r] = acc[mi][ni][r] + bvf;
            acc[mi][ni][r] = 0.f;
          }
        }
      }
    }

    __syncthreads();
    buf ^= 1;
  }

  // dense coalesced store with relu. C/D: col=lane&15, row=(lane>>4)*4+reg
#pragma unroll
  for (int ni = 0; ni < 4; ++ni) {
    int col = nBase + wn + ni * 16 + fr;
#pragma unroll
    for (int mi = 0; mi < 4; ++mi) {
      int row0 = mBase + wm + mi * 16 + fq * 4;
#pragma unroll
      for (int r = 0; r < 4; ++r) {
        float o = res[mi][ni][r];
        __builtin_nontemporal_store(o > 0.f ? o : 0.f,
                                    &out[(size_t)(row0 + r) * E_DIM + col]);
      }
    }
  }
}

extern "C" void kernel_launch(void* const* d_in, const int* in_sizes, int n_in,
                              void* d_out, int out_size, void* d_ws, size_t ws_size,
                              hipStream_t stream) {
  const float* x[4]; const float* W[4]; const float* bs[4];
  for (int f = 0; f < 4; ++f) {
    x[f]  = (const float*)d_in[3 * f + 0];
    W[f]  = (const float*)d_in[3 * f + 1];
    bs[f] = (const float*)d_in[3 * f + 2];
  }
  char* ws = (char*)d_ws;
  uint16_t* xb  = (uint16_t*)ws;                               // 32 MB
  uint16_t* Wt  = (uint16_t*)(ws + (size_t)32 * 1024 * 1024);  // 16 MB
  uint8_t*  idx1 = (uint8_t*)(ws + (size_t)48 * 1024 * 1024);  //  2 MB
  float* out = (float*)d_out;

  prep_kernel<<<dim3(8192), dim3(256), 0, stream>>>(
      x[0], x[1], x[2], x[3], W[0], W[1], W[2], W[3], xb, Wt, idx1);
  gemm_fused<<<dim3(E_DIM / 128, B_DIM / 128), dim3(256), 0, stream>>>(
      xb, Wt, (const uint32_t*)idx1, bs[0], bs[1], bs[2], bs[3], out);
}

// Round 9
// 278.175 us; speedup vs baseline: 1.4281x; 1.4281x over previous
//
#include <hip/hip_runtime.h>
#include <stdint.h>

// ---------------------------------------------------------------------------
// EmbraceNet fused: out[b,e] = relu(x_f @ W_f + b_f)[b,e],  f = idx[b,e]
// idx = categorical(key=42): partitionable threefry, bits = y0^y1 of
// threefry2x32((0,42), (0, (e*4096+b)*4+f)); argmax over bits>>9, strict >.
// PASS since R4 (absmax 0.031).
//
// R19: R18 post-mortem -- __launch_bounds__(256,4) clamped the allocator
// to the 64-VGPR occupancy quantum (R17: 124) and spilled acc/res to
// scratch (FETCH 190MB, WRITE 145MB = spill signature; MfmaUtil 11.7%).
// The occupancy experiment never ran. Fix is one token: bound back to
// (256,2) -- a MINIMUM-occupancy hint, not a block cap. R17's natural
// 124 VGPR already permits 4 waves/SIMD (m69: halves at 128); with BK=32's
// 32 KiB LDS the hardware can now co-schedule 4 blocks/CU (vs R17's 2,
// LDS-capped at 64 KiB). Everything else == R18 == R17 skeleton at BK=32:
// plain __syncthreads double-buffer, stage-next-then-compute, R13-verified
// staging (LDS row = 4 slots x 16B, slot^((row>>1)&3) XOR, pre-swizzled
// global source), register selection-fold at plane boundaries, dense
// epilogue, bijective XCD swizzle.
// ---------------------------------------------------------------------------

typedef short short8 __attribute__((ext_vector_type(8)));
typedef float floatx4 __attribute__((ext_vector_type(4)));

#define B_DIM 4096
#define K_DIM 1024
#define E_DIM 2048

__device__ __forceinline__ uint32_t rotl32(uint32_t x, uint32_t r) {
  return __builtin_amdgcn_alignbit(x, x, 32u - r);
}

__device__ __forceinline__ uint16_t f2bf(float x) {
  uint32_t u = __float_as_uint(x);
  u += 0x7FFFu + ((u >> 16) & 1u);
  return (uint16_t)(u >> 16);
}

// JAX threefry2x32, key = (0, 42)
__device__ __forceinline__ void threefry(uint32_t x0, uint32_t x1,
                                         uint32_t& o0, uint32_t& o1) {
  const uint32_t ks0 = 0u;
  const uint32_t ks1 = 42u;
  const uint32_t ks2 = 0x1BD11BDAu ^ 42u;
  x0 += ks0; x1 += ks1;
#define TF_R(r) { x0 += x1; x1 = rotl32(x1, r); x1 ^= x0; }
  TF_R(13) TF_R(15) TF_R(26) TF_R(6)
  x0 += ks1; x1 += ks2 + 1u;
  TF_R(17) TF_R(29) TF_R(16) TF_R(24)
  x0 += ks2; x1 += ks0 + 2u;
  TF_R(13) TF_R(15) TF_R(26) TF_R(6)
  x0 += ks0; x1 += ks1 + 3u;
  TF_R(17) TF_R(29) TF_R(16) TF_R(24)
  x0 += ks1; x1 += ks2 + 4u;
  TF_R(13) TF_R(15) TF_R(26) TF_R(6)
  x0 += ks2; x1 += ks0 + 5u;
#undef TF_R
  o0 = x0; o1 = x1;
}

// 8192 blocks x 256 threads. Every thread: issue x loads (8 floats) + W
// loads (4 floats), crunch 4 idx outputs (16 threefry) while loads fly,
// then store x bf16 (16B), idx byte, and W transposed tile via LDS.
__global__ __launch_bounds__(256) void prep_kernel(
    const float* __restrict__ x0, const float* __restrict__ x1,
    const float* __restrict__ x2, const float* __restrict__ x3,
    const float* __restrict__ W0, const float* __restrict__ W1,
    const float* __restrict__ W2, const float* __restrict__ W3,
    uint16_t* __restrict__ xb, uint16_t* __restrict__ Wt,
    uint8_t* __restrict__ idx1) {
  __shared__ float tile[32][33];
  const uint32_t g = blockIdx.x;       // 0..8191
  const int t = threadIdx.x;
  const int f = g >> 11;               // plane 0..3
  const uint32_t ip = g & 2047u;       // tile/chunk within plane

  // ---- issue x loads: plane f, 8 consecutive floats per thread ----
  const float* x = (f == 0) ? x0 : (f == 1) ? x1 : (f == 2) ? x2 : x3;
  const size_t xoff = ((size_t)ip * 256 + t) * 8;
  float4 v0 = *(const float4*)(x + xoff);
  float4 v1 = *(const float4*)(x + xoff + 4);

  // ---- issue W loads: 32x32 tile ip of plane f ----
  const float* W = (f == 0) ? W0 : (f == 1) ? W1 : (f == 2) ? W2 : W3;
  const int e0 = (int)(ip & 63) * 32, k0 = (int)(ip >> 6) * 32;
  const int tx = t & 31, ty = t >> 5;
  float wv[4];
#pragma unroll
  for (int i = 0; i < 4; ++i)
    wv[i] = W[(size_t)(k0 + ty + i * 8) * E_DIM + e0 + tx];

  // ---- threefry crunch: outputs o0..o0+3, pack 2 bits each ----
  const uint32_t o0i = (g * 256u + t) * 4u;
  uint32_t byte = 0;
#pragma unroll
  for (uint32_t q = 0; q < 4; ++q) {
    uint32_t c = (o0i + q) << 2;
    uint32_t best = 0, bi = 0;
#pragma unroll
    for (uint32_t ff = 0; ff < 4; ++ff) {
      uint32_t y0, y1;
      threefry(0u, c + ff, y0, y1);
      uint32_t m = (y0 ^ y1) >> 9;
      if (ff == 0) best = m;
      else if (m > best) { best = m; bi = ff; }
    }
    byte |= bi << (2 * q);
  }
  idx1[g * 256u + t] = (uint8_t)byte;

  // ---- x store: 8 bf16 = 16B ----
  {
    union { uint16_t h[8]; uint64_t q[2]; } p;
    p.h[0] = f2bf(v0.x); p.h[1] = f2bf(v0.y);
    p.h[2] = f2bf(v0.z); p.h[3] = f2bf(v0.w);
    p.h[4] = f2bf(v1.x); p.h[5] = f2bf(v1.y);
    p.h[6] = f2bf(v1.z); p.h[7] = f2bf(v1.w);
    uint64_t* dst = (uint64_t*)(xb + (size_t)f * B_DIM * K_DIM + xoff);
    dst[0] = p.q[0]; dst[1] = p.q[1];
  }

  // ---- W transpose via LDS ----
#pragma unroll
  for (int i = 0; i < 4; ++i) tile[ty + i * 8][tx] = wv[i];
  __syncthreads();
  {
    const int el = t >> 3, kc = (t & 7) * 4;
    union { uint16_t h[4]; uint64_t q; } p;
#pragma unroll
    for (int i = 0; i < 4; ++i) p.h[i] = f2bf(tile[kc + i][el]);
    uint16_t* dst = Wt + (size_t)f * E_DIM * K_DIM;
    *(uint64_t*)(dst + (size_t)(e0 + el) * K_DIM + k0 + kc) = p.q;
  }
}

__device__ __forceinline__ void async16(const uint16_t* g, uint16_t* lds) {
  __builtin_amdgcn_global_load_lds(
      (const __attribute__((address_space(1))) void*)g,
      (__attribute__((address_space(3))) void*)lds, 16, 0, 0);
}

#define PLANE_A ((size_t)B_DIM * K_DIM)
#define PLANE_B ((size_t)E_DIM * K_DIM)
#define BK 32

// 256 threads (4 waves, 2x2 of 64x64), 128x128 tile, BK=32 double-buffered
// LDS (32 KiB -> up to 4 blocks/CU at VGPR<=128), flat 128-step loop
// (f = j>>5), one __syncthreads per step. LDS row = 32 bf16 (64 B) =
// 4 slots x 16B; slot holds global k-chunk slot^((row>>1)&3).
__global__ __launch_bounds__(256, 2) void gemm_fused(
    const uint16_t* __restrict__ Ab, const uint16_t* __restrict__ Bbt,
    const uint32_t* __restrict__ idx2,
    const float* __restrict__ bias0, const float* __restrict__ bias1,
    const float* __restrict__ bias2, const float* __restrict__ bias3,
    float* __restrict__ out) {
  __shared__ uint16_t As[2][128 * BK];   // 2 x 8 KiB
  __shared__ uint16_t Bs[2][128 * BK];   // 2 x 8 KiB

  const int tid = threadIdx.x;
  const int w = tid >> 6;        // 0..3
  const int l = tid & 63;

  // bijective XCD-chunked swizzle: 512 blocks = 8 XCDs x 64 contiguous
  const int flat = (int)(blockIdx.y * gridDim.x + blockIdx.x);
  const int swz = (flat & 7) * 64 + (flat >> 3);
  const int mBase = (swz >> 4) * 128;   // 32 m-tiles
  const int nBase = (swz & 15) * 128;   // 16 n-tiles

  const int wm = (w >> 1) * 64, wn = (w & 1) * 64;
  const int fr = l & 15, fq = l >> 4;

  // staging (R13-verified): lane l -> row sRow = l>>2 (of 16-row group),
  // slot = l&3; global k-chunk = slot ^ ((sRow>>1)&3).
  const int sRow = l >> 2;
  const int gck = ((l & 3) ^ ((sRow >> 1) & 3)) * 8;
  const uint16_t* aBase = Ab + (size_t)(mBase + 32 * w + sRow) * K_DIM + gck;
  const uint16_t* bBase = Bbt + (size_t)(nBase + 32 * w + sRow) * K_DIM + gck;

  // read-side: slot for global chunk fq of row (row bits 2:1 == fr bits)
  const int kread = (fq ^ ((fr >> 1) & 3)) * 8;

  // stage 32-K step t into buffer bf: 2 A-instrs + 2 B-instrs per wave
  auto stage = [&](int t, int bf) {
    const int f = t >> 5, ko = (t & 31) * BK;
    const uint16_t* pA = aBase + (size_t)f * PLANE_A + ko;
    const uint16_t* pB = bBase + (size_t)f * PLANE_B + ko;
    async16(pA, &As[bf][(2 * w + 0) * 512]);
    async16(pA + (size_t)16 * K_DIM, &As[bf][(2 * w + 1) * 512]);
    async16(pB, &Bs[bf][(2 * w + 0) * 512]);
    async16(pB + (size_t)16 * K_DIM, &Bs[bf][(2 * w + 1) * 512]);
  };

  // selection words in regs
  const int b_hi0 = (mBase + wm) >> 4;
  uint32_t iw[4][4];
#pragma unroll
  for (int ni = 0; ni < 4; ++ni) {
    int col = nBase + wn + ni * 16 + fr;
#pragma unroll
    for (int mi = 0; mi < 4; ++mi)
      iw[ni][mi] = idx2[(size_t)col * (B_DIM / 16) + b_hi0 + mi];
  }

  floatx4 acc[4][4] = {};
  floatx4 res[4][4] = {};

  stage(0, 0);
  __syncthreads();

  int buf = 0;
#pragma unroll 1
  for (int j = 0; j < 128; ++j) {
    if (j + 1 < 128) stage(j + 1, buf ^ 1);

    short8 a[4], b[4];
#pragma unroll
    for (int mi = 0; mi < 4; ++mi)
      a[mi] = *(const short8*)&As[buf][(wm + mi * 16 + fr) * BK + kread];
#pragma unroll
    for (int ni = 0; ni < 4; ++ni)
      b[ni] = *(const short8*)&Bs[buf][(wn + ni * 16 + fr) * BK + kread];
#pragma unroll
    for (int mi = 0; mi < 4; ++mi)
#pragma unroll
      for (int ni = 0; ni < 4; ++ni)
        acc[mi][ni] = __builtin_amdgcn_mfma_f32_16x16x32_bf16(
            a[mi], b[ni], acc[mi][ni], 0, 0, 0);

    // plane boundary: register-only selection fold, reset acc
    if ((j & 31) == 31) {
      const int f = j >> 5;
      const float* bias = (f == 0) ? bias0 : (f == 1) ? bias1
                        : (f == 2) ? bias2 : bias3;
#pragma unroll
      for (int ni = 0; ni < 4; ++ni) {
        float bvf = bias[nBase + wn + ni * 16 + fr];
#pragma unroll
        for (int mi = 0; mi < 4; ++mi) {
          uint32_t wd = iw[ni][mi];
#pragma unroll
          for (int r = 0; r < 4; ++r) {
            uint32_t sel = (wd >> (2 * (fq * 4 + r))) & 3u;
            if (sel == (uint32_t)f) res[mi][ni][r] = acc[mi][ni][r] + bvf;
            acc[mi][ni][r] = 0.f;
          }
        }
      }
    }

    __syncthreads();
    buf ^= 1;
  }

  // dense coalesced store with relu. C/D: col=lane&15, row=(lane>>4)*4+reg
#pragma unroll
  for (int ni = 0; ni < 4; ++ni) {
    int col = nBase + wn + ni * 16 + fr;
#pragma unroll
    for (int mi = 0; mi < 4; ++mi) {
      int row0 = mBase + wm + mi * 16 + fq * 4;
#pragma unroll
      for (int r = 0; r < 4; ++r) {
        float o = res[mi][ni][r];
        __builtin_nontemporal_store(o > 0.f ? o : 0.f,
                                    &out[(size_t)(row0 + r) * E_DIM + col]);
      }
    }
  }
}

extern "C" void kernel_launch(void* const* d_in, const int* in_sizes, int n_in,
                              void* d_out, int out_size, void* d_ws, size_t ws_size,
                              hipStream_t stream) {
  const float* x[4]; const float* W[4]; const float* bs[4];
  for (int f = 0; f < 4; ++f) {
    x[f]  = (const float*)d_in[3 * f + 0];
    W[f]  = (const float*)d_in[3 * f + 1];
    bs[f] = (const float*)d_in[3 * f + 2];
  }
  char* ws = (char*)d_ws;
  uint16_t* xb  = (uint16_t*)ws;                               // 32 MB
  uint16_t* Wt  = (uint16_t*)(ws + (size_t)32 * 1024 * 1024);  // 16 MB
  uint8_t*  idx1 = (uint8_t*)(ws + (size_t)48 * 1024 * 1024);  //  2 MB
  float* out = (float*)d_out;

  prep_kernel<<<dim3(8192), dim3(256), 0, stream>>>(
      x[0], x[1], x[2], x[3], W[0], W[1], W[2], W[3], xb, Wt, idx1);
  gemm_fused<<<dim3(E_DIM / 128, B_DIM / 128), dim3(256), 0, stream>>>(
      xb, Wt, (const uint32_t*)idx1, bs[0], bs[1], bs[2], bs[3], out);
}